// Round 8
// baseline (1653.600 us; speedup 1.0000x reference)
//
#include <hip/hip_runtime.h>
#include <math.h>

// Problem constants (from reference)
#define TT 2048
#define BB 512
#define II 11
#define HH 33
#define NL 3
#define OO 18
#define SLOT 36           // padded vector stride in floats (144 B, 16B-aligned slots)

typedef float f2 __attribute__((ext_vector_type(2)));
typedef float f4 __attribute__((ext_vector_type(4)));

// fast sigmoid via v_exp_f32 + v_rcp_f32 (saturates correctly at +-inf)
__device__ __forceinline__ float sigm_f(float x) {
    float e = __expf(-x);
    return __builtin_amdgcn_rcpf(1.0f + e);
}
__device__ __forceinline__ float tanh_f(float x) {
    float e = __expf(2.0f * x);
    return 1.0f - 2.0f * __builtin_amdgcn_rcpf(e + 1.0f);
}

// DPP quad_perm exchanges (VALU pipe, no LDS): xor1=[1,0,3,2]=0xB1, xor2=[2,3,0,1]=0x4E
__device__ __forceinline__ float dpp_xor1(float v) {
    return __builtin_bit_cast(float,
        __builtin_amdgcn_update_dpp(0, __builtin_bit_cast(int, v), 0xB1, 0xF, 0xF, true));
}
__device__ __forceinline__ float dpp_xor2(float v) {
    return __builtin_bit_cast(float,
        __builtin_amdgcn_update_dpp(0, __builtin_bit_cast(int, v), 0x4E, 0xF, 0xF, true));
}

// guarded 4-float load: element k0+i valid iff k0+i < rem (zero-pad otherwise)
__device__ __forceinline__ f4 gld4(const float* p, int k0, int rem) {
    f4 v;
    v.x = (k0 + 0 < rem) ? p[k0 + 0] : 0.0f;
    v.y = (k0 + 1 < rem) ? p[k0 + 1] : 0.0f;
    v.z = (k0 + 2 < rem) ? p[k0 + 2] : 0.0f;
    v.w = (k0 + 3 < rem) ? p[k0 + 3] : 0.0f;
    return v;
}

// Layer-pipelined LSTM, COLUMN-SPLIT quads (R4 structure), fp32 pk_fma,
// AGPR tax removed via __launch_bounds__(448,2), activation dedupe (1/lane),
// steady-state peeling (no exec-mask churn in 2045 of 2050 supersteps).
// grid = 512 blocks (one batch element each), block = 448 threads (7 waves).
//   tid < 396 : u = tid>>2 (unit 0..98), q = tid&3 (column-quarter).
//     q0: in[0:16), q1: in[16:32)+in[32], q2: h[0:16), q3: h[16:32)+h[32]
//     Lane accumulates partials of ALL 4 gate rows over its slice (32 pk_fma
//     + 4 fma), quad all-reduce via DPP, then lane q activates ONLY gate q
//     (tanh via 2*sigm(2x)-1 for q==2), 3 DPP + 12 cndmask redistribute.
//   tid 396..406 : x prefetchers (11 features), 2-deep software pipeline.
// LDS: ping-pong buf[2][4][SLOT]; one barrier per superstep.
__global__ __launch_bounds__(448, 2) void lstm_pipeline_kernel(
    const float* __restrict__ x,
    const float* __restrict__ Wih0, const float* __restrict__ Whh0,
    const float* __restrict__ bih0, const float* __restrict__ bhh0,
    const float* __restrict__ Wih1, const float* __restrict__ Whh1,
    const float* __restrict__ bih1, const float* __restrict__ bhh1,
    const float* __restrict__ Wih2, const float* __restrict__ Whh2,
    const float* __restrict__ bih2, const float* __restrict__ bhh2,
    float* __restrict__ hidden_out)   // [3, 512, 33]
{
    __shared__ __align__(16) float buf[2][NL + 1][SLOT];

    const int tid = threadIdx.x;
    const int bg  = blockIdx.x;

    for (int i = tid; i < 2 * (NL + 1) * SLOT; i += 448)
        ((float*)buf)[i] = 0.0f;

    const bool comp = (tid < 396);
    const int  u    = tid >> 2;          // unit 0..98
    const int  q    = tid & 3;           // column-quarter / gate owner
    const int  l    = (u < 33) ? 0 : (u < 66) ? 1 : 2;
    const int  j    = u - 33 * l;

    const int  pi   = tid - 396;
    const bool pref = (pi >= 0) && (pi < II);
    const float* xrow = x + (size_t)bg * TT * II + (pref ? pi : 0);

    // ---- per-lane weights: 4 gate rows x 16-col slice (+1 col on odd q) ----
    f4 w0a = {0,0,0,0}, w0b = w0a, w0c = w0a, w0d = w0a;   // gate 0 (i)
    f4 w1a = w0a, w1b = w0a, w1c = w0a, w1d = w0a;         // gate 1 (f)
    f4 w2a = w0a, w2b = w0a, w2c = w0a, w2d = w0a;         // gate 2 (g)
    f4 w3a = w0a, w3b = w0a, w3c = w0a, w3d = w0a;         // gate 3 (o)
    float we0 = 0.0f, we1 = 0.0f, we2 = 0.0f, we3 = 0.0f;  // col-32 (odd q)
    float b_sel = 0.0f;                                    // bias of gate q only

    if (comp) {
        const float* bip = (l == 0) ? bih0 : (l == 1) ? bih1 : bih2;
        const float* bhp = (l == 0) ? bhh0 : (l == 1) ? bhh1 : bhh2;
        b_sel = bip[q * HH + j] + bhp[q * HH + j];

        const float* Wsrc;
        int kin, cbase;
        if (q < 2) {   // slice of W_ih
            kin   = (l == 0) ? II : HH;
            Wsrc  = (l == 0) ? Wih0 : (l == 1) ? Wih1 : Wih2;
            cbase = 16 * q;
        } else {       // slice of W_hh
            kin   = HH;
            Wsrc  = (l == 0) ? Whh0 : (l == 1) ? Whh1 : Whh2;
            cbase = 16 * (q - 2);
        }
        const int rem = kin - cbase;
        const float* r0 = Wsrc + (0 * HH + j) * kin + cbase;
        const float* r1 = Wsrc + (1 * HH + j) * kin + cbase;
        const float* r2 = Wsrc + (2 * HH + j) * kin + cbase;
        const float* r3 = Wsrc + (3 * HH + j) * kin + cbase;
        w0a = gld4(r0, 0, rem); w0b = gld4(r0, 4, rem); w0c = gld4(r0, 8, rem); w0d = gld4(r0, 12, rem);
        w1a = gld4(r1, 0, rem); w1b = gld4(r1, 4, rem); w1c = gld4(r1, 8, rem); w1d = gld4(r1, 12, rem);
        w2a = gld4(r2, 0, rem); w2b = gld4(r2, 4, rem); w2c = gld4(r2, 8, rem); w2d = gld4(r2, 12, rem);
        w3a = gld4(r3, 0, rem); w3b = gld4(r3, 4, rem); w3c = gld4(r3, 8, rem); w3d = gld4(r3, 12, rem);
        if ((q & 1) && kin > 32) {
            we0 = Wsrc[(0 * HH + j) * kin + 32];
            we1 = Wsrc[(1 * HH + j) * kin + 32];
            we2 = Wsrc[(2 * HH + j) * kin + 32];
            we3 = Wsrc[(3 * HH + j) * kin + 32];
        }
    }

    __syncthreads();
    float v_next = 0.0f, v_next2 = 0.0f;
    if (pref) {
        buf[0][0][pi] = xrow[0];
        v_next  = xrow[II];
        v_next2 = xrow[2 * II];
    }
    __syncthreads();

    float c = 0.0f;
    const int   vsel = (q < 2) ? l : (l + 1);     // LDS slot this lane reads
    const float mA   = (q == 2) ? 2.0f : 1.0f;    // q2 activates via tanh form
    const float cAc  = (q == 2) ? -1.0f : 0.0f;
    const bool  qb0  = (q & 1), qb1 = (q & 2);

    // one superstep; `check`/`out` are compile-time-constant at every call site
    auto step = [&](int s, int rp, bool check, bool out) {
        const int wp = rp ^ 1;
        if (pref) {   // wave-6 only; execz-skipped elsewhere
            if (s + 1 < TT) buf[wp][0][pi] = v_next;
            v_next = v_next2;
            if (s + 3 < TT) v_next2 = xrow[(size_t)(s + 3) * II];
        }
        const bool active = comp && (!check || ((s >= l) && (s - l < TT)));
        if (active) {
            const f4* V = (const f4*)(&buf[rp][vsel][(q & 1) * 16]);
            const f4 v0 = V[0], v1 = V[1], v2 = V[2], v3 = V[3];
            const float vex = buf[rp][vsel][32];

            f2 a0 = {0.0f, 0.0f}, a1 = a0, a2 = a0, a3 = a0;
            a0 += v0.xy * w0a.xy; a0 += v0.zw * w0a.zw;
            a1 += v0.xy * w1a.xy; a1 += v0.zw * w1a.zw;
            a2 += v0.xy * w2a.xy; a2 += v0.zw * w2a.zw;
            a3 += v0.xy * w3a.xy; a3 += v0.zw * w3a.zw;
            a0 += v1.xy * w0b.xy; a0 += v1.zw * w0b.zw;
            a1 += v1.xy * w1b.xy; a1 += v1.zw * w1b.zw;
            a2 += v1.xy * w2b.xy; a2 += v1.zw * w2b.zw;
            a3 += v1.xy * w3b.xy; a3 += v1.zw * w3b.zw;
            a0 += v2.xy * w0c.xy; a0 += v2.zw * w0c.zw;
            a1 += v2.xy * w1c.xy; a1 += v2.zw * w1c.zw;
            a2 += v2.xy * w2c.xy; a2 += v2.zw * w2c.zw;
            a3 += v2.xy * w3c.xy; a3 += v2.zw * w3c.zw;
            a0 += v3.xy * w0d.xy; a0 += v3.zw * w0d.zw;
            a1 += v3.xy * w1d.xy; a1 += v3.zw * w1d.zw;
            a2 += v3.xy * w2d.xy; a2 += v3.zw * w2d.zw;
            a3 += v3.xy * w3d.xy; a3 += v3.zw * w3d.zw;

            float g0 = (a0.x + a0.y) + vex * we0;
            float g1 = (a1.x + a1.y) + vex * we1;
            float g2 = (a2.x + a2.y) + vex * we2;
            float g3 = (a3.x + a3.y) + vex * we3;

            // quad all-reduce (full gate sums in every lane)
            g0 += dpp_xor1(g0); g0 += dpp_xor2(g0);
            g1 += dpp_xor1(g1); g1 += dpp_xor2(g1);
            g2 += dpp_xor1(g2); g2 += dpp_xor2(g2);
            g3 += dpp_xor1(g3); g3 += dpp_xor2(g3);

            // lane q activates ONLY gate q (q2: tanh via 2*sigm(2x)-1)
            const float a_sel = qb1 ? (qb0 ? g3 : g2) : (qb0 ? g1 : g0);
            const float act   = __builtin_fmaf(mA, sigm_f(mA * (a_sel + b_sel)), cAc);

            // redistribute the 4 activations (3 DPP + 12 cndmask)
            const float t1 = dpp_xor1(act);   // gate q^1
            const float t2 = dpp_xor2(act);   // gate q^2
            const float t3 = dpp_xor2(t1);    // gate q^3
            const float ig = qb1 ? (qb0 ? t3 : t2) : (qb0 ? t1 : act);
            const float fg = qb1 ? (qb0 ? t2 : t3) : (qb0 ? act : t1);
            const float gg = qb1 ? (qb0 ? t1 : act) : (qb0 ? t3 : t2);
            const float og = qb1 ? (qb0 ? act : t1) : (qb0 ? t2 : t3);

            c = __builtin_fmaf(fg, c, ig * gg);   // identical across the quad
            const float hnew = og * tanh_f(c);

            if (q == 0) {
                buf[wp][l + 1][j] = hnew;
                if (out && (s - l == TT - 1))
                    hidden_out[((size_t)l * BB + bg) * HH + j] = hnew;
            }
        }
        __syncthreads();
    };

    // prologue (pipeline fill, masked)
    step(0, 0, true, false);
    step(1, 1, true, false);
    // steady state: s = 2 .. TT-2, all comp lanes active, no outputs.
    // 2..2045 as constant-rp pairs, then single s=2046.
    for (int s = 2; s < TT - 2; s += 2) {
        step(s,     0, false, false);
        step(s + 1, 1, false, false);
    }
    step(TT - 2, 0, false, false);     // s=2046
    // epilogue (pipeline drain + final-h outputs)
    step(TT - 1, 1, false, true);      // s=2047: l0 writes hT
    step(TT,     0, true,  true);      // s=2048: l1 writes hT
    step(TT + 1, 1, true,  true);      // s=2049: l2 writes hT
}

// MLP head: hidden [3*512, 33] -> gelu(hidden@W1^T + b1) [.,72] -> @W2^T + b2 [.,18]
__global__ void mlp_head_kernel(const float* __restrict__ hidden,
                                const float* __restrict__ W1, const float* __restrict__ b1,
                                const float* __restrict__ W2, const float* __restrict__ b2,
                                float* __restrict__ out)
{
    const int row = blockIdx.x * blockDim.x + threadIdx.x;   // 0..1535
    if (row >= NL * BB) return;

    float hv[HH];
    #pragma unroll
    for (int k = 0; k < HH; ++k) hv[k] = hidden[row * HH + k];

    float h1[4 * OO];
    #pragma unroll
    for (int m = 0; m < 4 * OO; ++m) {
        float a = b1[m];
        #pragma unroll
        for (int k = 0; k < HH; ++k) a += hv[k] * W1[m * HH + k];
        h1[m] = 0.5f * a * (1.0f + erff(a * 0.70710678118654752f));
    }
    #pragma unroll
    for (int o = 0; o < OO; ++o) {
        float a = b2[o];
        #pragma unroll
        for (int m = 0; m < 4 * OO; ++m) a += h1[m] * W2[o * (4 * OO) + m];
        out[row * OO + o] = a;
    }
}

extern "C" void kernel_launch(void* const* d_in, const int* in_sizes, int n_in,
                              void* d_out, int out_size, void* d_ws, size_t ws_size,
                              hipStream_t stream) {
    const float* x    = (const float*)d_in[0];
    const float* Wih0 = (const float*)d_in[1];
    const float* Whh0 = (const float*)d_in[2];
    const float* bih0 = (const float*)d_in[3];
    const float* bhh0 = (const float*)d_in[4];
    const float* Wih1 = (const float*)d_in[5];
    const float* Whh1 = (const float*)d_in[6];
    const float* bih1 = (const float*)d_in[7];
    const float* bhh1 = (const float*)d_in[8];
    const float* Wih2 = (const float*)d_in[9];
    const float* Whh2 = (const float*)d_in[10];
    const float* bih2 = (const float*)d_in[11];
    const float* bhh2 = (const float*)d_in[12];
    const float* W1   = (const float*)d_in[13];
    const float* b1   = (const float*)d_in[14];
    const float* W2   = (const float*)d_in[15];
    const float* b2   = (const float*)d_in[16];

    float* out    = (float*)d_out;                 // [3,512,18] = 27648 floats
    float* hidden = out + NL * BB * OO;            // [3,512,33] = 50688 floats

    lstm_pipeline_kernel<<<BB, 448, 0, stream>>>(
        x, Wih0, Whh0, bih0, bhh0, Wih1, Whh1, bih1, bhh1,
        Wih2, Whh2, bih2, bhh2, hidden);

    mlp_head_kernel<<<(NL * BB + 255) / 256, 256, 0, stream>>>(
        hidden, W1, b1, W2, b2, out);
}

// Round 9
// 1189.809 us; speedup vs baseline: 1.3898x; 1.3898x over previous
//
#include <hip/hip_runtime.h>
#include <math.h>

// Problem constants (from reference)
#define TT 2048
#define BB 512
#define II 11
#define HH 33
#define NL 3
#define OO 18
#define HSLOT 48          // halves per LDS vector slot (96 B, 16B-aligned slots)

typedef _Float16 h4 __attribute__((ext_vector_type(4)));
typedef _Float16 h8 __attribute__((ext_vector_type(8)));   // 16 B -> ds_read_b128

// fast sigmoid / tanh via v_exp_f32 + v_rcp_f32 (saturate correctly at +-inf)
__device__ __forceinline__ float sigm_f(float x) {
    float e = __expf(-x);
    return __builtin_amdgcn_rcpf(1.0f + e);
}
__device__ __forceinline__ float tanh_f(float x) {
    float e = __expf(2.0f * x);
    return 1.0f - 2.0f * __builtin_amdgcn_rcpf(e + 1.0f);
}

// DPP quad_perm [1,0,3,2]: exchange within adjacent lane pairs (VALU pipe, no LDS)
__device__ __forceinline__ float dpp_xor1(float v) {
    return __builtin_bit_cast(float,
        __builtin_amdgcn_update_dpp(0, __builtin_bit_cast(int, v), 0xB1, 0xF, 0xF, true));
}

// guarded fp32->fp16 row-slice loads (zero-pad past rem)
__device__ __forceinline__ h8 gldh8(const float* p, int k0, int rem) {
    h8 v;
    #pragma unroll
    for (int i = 0; i < 8; ++i) v[i] = (_Float16)((k0 + i < rem) ? p[k0 + i] : 0.0f);
    return v;
}
__device__ __forceinline__ h4 gldh4(const float* p, int k0, int rem) {
    h4 v;
    #pragma unroll
    for (int i = 0; i < 4; ++i) v[i] = (_Float16)((k0 + i < rem) ? p[k0 + i] : 0.0f);
    return v;
}

// v_dot2_f32_f16 chains: 2 MACs/op, fp32 accumulate
#define D8(a, v, w) do { \
    a = __builtin_amdgcn_fdot2((v).s01, (w).s01, a, false); \
    a = __builtin_amdgcn_fdot2((v).s23, (w).s23, a, false); \
    a = __builtin_amdgcn_fdot2((v).s45, (w).s45, a, false); \
    a = __builtin_amdgcn_fdot2((v).s67, (w).s67, a, false); } while (0)
#define D4(a, v, w) do { \
    a = __builtin_amdgcn_fdot2((v).s01, (w).s01, a, false); \
    a = __builtin_amdgcn_fdot2((v).s23, (w).s23, a, false); } while (0)

// Layer-pipelined LSTM: R6 pair-split/fp16-fdot2 base + R8 steady-state peeling.
// grid = 512 blocks (one batch element each), block = 256 threads (4 waves).
//   tid < 198 : u = tid>>1 (unit 0..98), p = tid&1 (role). l = u/33, j = u%33.
//     p=0: reads layer INPUT vector (slot l), holds the 4 W_ih gate rows.
//     p=1: reads OWN-h vector (slot l+1), holds the 4 W_hh gate rows.
//     72 fdot2 partial dots -> pair all-reduce (4 DPP adds) -> activation
//     dedupe (p0: i,f; p1: g,o via tanh(x)=2*sigm(2x)-1) -> c,h (both lanes).
//   tid 198..208 : x prefetchers (11 features), 2-deep software pipeline.
// Peeling: supersteps 2..2046 run with compile-time ping-pong pointers and no
// active-mask/output checks (only prologue 0..1 and epilogue 2047..2049 check).
// LDS: ping-pong buf[2][4][HSLOT] halves; one barrier per superstep.
__global__ __launch_bounds__(256, 2) void lstm_pipeline_kernel(
    const float* __restrict__ x,
    const float* __restrict__ Wih0, const float* __restrict__ Whh0,
    const float* __restrict__ bih0, const float* __restrict__ bhh0,
    const float* __restrict__ Wih1, const float* __restrict__ Whh1,
    const float* __restrict__ bih1, const float* __restrict__ bhh1,
    const float* __restrict__ Wih2, const float* __restrict__ Whh2,
    const float* __restrict__ bih2, const float* __restrict__ bhh2,
    float* __restrict__ hidden_out)   // [3, 512, 33]
{
    __shared__ __align__(16) _Float16 buf[2][NL + 1][HSLOT];

    const int tid = threadIdx.x;
    const int bg  = blockIdx.x;

    for (int i = tid; i < 2 * (NL + 1) * HSLOT; i += 256)
        ((_Float16*)buf)[i] = (_Float16)0.0f;

    const bool comp = (tid < 198);
    const int  u    = tid >> 1;          // unit 0..98
    const int  p    = tid & 1;           // 0 = input-role, 1 = h-role
    const int  l    = (u < 33) ? 0 : (u < 66) ? 1 : 2;
    const int  j    = u - 33 * l;

    const int  pi   = tid - 198;
    const bool pref = (pi >= 0) && (pi < II);
    const float* xrow = x + (size_t)bg * TT * II + (pref ? pi : 0);

    // ---- per-lane weights: 4 gate rows x 36 cols, packed fp16 = 36 VGPRs ----
    h8 z8 = {0,0,0,0,0,0,0,0};
    h4 z4 = {0,0,0,0};
    h8 w0a=z8,w0b=z8,w0c=z8,w0d=z8; h4 w0t=z4;   // gate i
    h8 w1a=z8,w1b=z8,w1c=z8,w1d=z8; h4 w1t=z4;   // gate f
    h8 w2a=z8,w2b=z8,w2c=z8,w2d=z8; h4 w2t=z4;   // gate g
    h8 w3a=z8,w3b=z8,w3c=z8,w3d=z8; h4 w3t=z4;   // gate o
    float b0 = 0.0f, b1 = 0.0f, b2 = 0.0f, b3 = 0.0f;

    if (comp) {
        const float* bip = (l == 0) ? bih0 : (l == 1) ? bih1 : bih2;
        const float* bhp = (l == 0) ? bhh0 : (l == 1) ? bhh1 : bhh2;
        if (p == 0) {   // bias once per pair; the all-reduce restores both lanes
            b0 = bip[0 * HH + j] + bhp[0 * HH + j];
            b1 = bip[1 * HH + j] + bhp[1 * HH + j];
            b2 = bip[2 * HH + j] + bhp[2 * HH + j];
            b3 = bip[3 * HH + j] + bhp[3 * HH + j];
        }
        const float* Wsrc = p ? ((l == 0) ? Whh0 : (l == 1) ? Whh1 : Whh2)
                              : ((l == 0) ? Wih0 : (l == 1) ? Wih1 : Wih2);
        const int kin = (p || l != 0) ? HH : II;
        const float* r0 = Wsrc + (0 * HH + j) * kin;
        const float* r1 = Wsrc + (1 * HH + j) * kin;
        const float* r2 = Wsrc + (2 * HH + j) * kin;
        const float* r3 = Wsrc + (3 * HH + j) * kin;
        w0a = gldh8(r0, 0, kin); w0b = gldh8(r0, 8, kin);
        w0c = gldh8(r0, 16, kin); w0d = gldh8(r0, 24, kin); w0t = gldh4(r0, 32, kin);
        w1a = gldh8(r1, 0, kin); w1b = gldh8(r1, 8, kin);
        w1c = gldh8(r1, 16, kin); w1d = gldh8(r1, 24, kin); w1t = gldh4(r1, 32, kin);
        w2a = gldh8(r2, 0, kin); w2b = gldh8(r2, 8, kin);
        w2c = gldh8(r2, 16, kin); w2d = gldh8(r2, 24, kin); w2t = gldh4(r2, 32, kin);
        w3a = gldh8(r3, 0, kin); w3b = gldh8(r3, 8, kin);
        w3c = gldh8(r3, 16, kin); w3d = gldh8(r3, 24, kin); w3t = gldh4(r3, 32, kin);
    }

    __syncthreads();
    float v_next = 0.0f, v_next2 = 0.0f;
    if (pref) {
        buf[0][0][pi] = (_Float16)xrow[0];
        v_next  = xrow[II];
        v_next2 = xrow[2 * II];
    }
    __syncthreads();

    float c = 0.0f;
    const int   vsel = p ? (l + 1) : l;      // which LDS slot this lane reads
    const float mA   = 1.0f + (float)p;      // activation-a: 1 -> sigm, 2 -> tanh
    const float cAc  = -(float)p;
    const bool  wrh  = comp && (p == 0);     // h-writer lanes

    // hoisted ping-pong pointers (compile-time selected in peeled steps)
    const _Float16* rd[2]  = { &buf[0][vsel][0], &buf[1][vsel][0] };
    _Float16*       wrp[2] = { &buf[0][l + 1][j], &buf[1][l + 1][j] };
    _Float16*       pxp[2] = { &buf[0][0][pi], &buf[1][0][pi] };

    // one superstep; all bool/int args are compile-time constants at call sites
    auto step = [&](int s, int rp, bool check, bool out, bool xload, bool xstore)
        __attribute__((always_inline)) {
        const int wp = rp ^ 1;
        if (pref) {
            if (xstore) *pxp[wp] = (_Float16)v_next;
            v_next = v_next2;
            if (xload) v_next2 = xrow[(size_t)(s + 3) * II];
        }
        const bool active = check ? (comp && (s >= l) && (s - l < TT)) : comp;
        if (active) {
            const _Float16* V16 = rd[rp];
            const h8* V = (const h8*)V16;
            const h8 v0 = V[0], v1 = V[1], v2 = V[2], v3 = V[3];
            const h4 vt = *(const h4*)(V16 + 32);

            float a0 = b0, a1 = b1, a2 = b2, a3 = b3;
            D8(a0, v0, w0a); D8(a1, v0, w1a); D8(a2, v0, w2a); D8(a3, v0, w3a);
            D8(a0, v1, w0b); D8(a1, v1, w1b); D8(a2, v1, w2b); D8(a3, v1, w3b);
            D8(a0, v2, w0c); D8(a1, v2, w1c); D8(a2, v2, w2c); D8(a3, v2, w3c);
            D8(a0, v3, w0d); D8(a1, v3, w1d); D8(a2, v3, w2d); D8(a3, v3, w3d);
            D4(a0, vt, w0t); D4(a1, vt, w1t); D4(a2, vt, w2t); D4(a3, vt, w3t);

            // pair all-reduce: full gate pre-activations in both lanes
            a0 += dpp_xor1(a0); a1 += dpp_xor1(a1);
            a2 += dpp_xor1(a2); a3 += dpp_xor1(a3);

            // activation dedupe: p0 activates i,f; p1 activates g,o
            const float aA = p ? a2 : a0;
            const float aB = p ? a3 : a1;
            const float acta = __builtin_fmaf(mA, sigm_f(mA * aA), cAc); // i or g
            const float actb = sigm_f(aB);                               // f or o
            const float xa = dpp_xor1(acta);
            const float xb = dpp_xor1(actb);
            const float ig = p ? xa : acta;
            const float gg = p ? acta : xa;
            const float fg = p ? xb : actb;
            const float og = p ? actb : xb;

            c = __builtin_fmaf(fg, c, ig * gg);   // identical in both lanes (fp32)
            const float hnew = og * tanh_f(c);

            if (wrh) {
                *wrp[wp] = (_Float16)hnew;
                if (out && (s - l == TT - 1))
                    hidden_out[((size_t)l * BB + bg) * HH + j] = hnew;
            }
        }
        __syncthreads();
    };

    // prologue (pipeline fill, masked)
    step(0, 0, true, false, true, true);
    step(1, 1, true, false, true, true);
    // steady state: s = 2..2043 as constant-rp pairs (no checks, no outputs)
    for (int s = 2; s < TT - 4; s += 2) {
        step(s,     0, false, false, true, true);
        step(s + 1, 1, false, false, true, true);
    }
    // tail of steady state + epilogue (drain + final-h outputs)
    step(TT - 4, 0, false, false, true,  true);    // s=2044 (last x load)
    step(TT - 3, 1, false, false, false, true);    // s=2045
    step(TT - 2, 0, false, false, false, true);    // s=2046 (stores x[2047])
    step(TT - 1, 1, false, true,  false, false);   // s=2047: l0 writes hT
    step(TT,     0, true,  true,  false, false);   // s=2048: l1 writes hT
    step(TT + 1, 1, true,  true,  false, false);   // s=2049: l2 writes hT
}

// MLP head: hidden [3*512, 33] -> gelu(hidden@W1^T + b1) [.,72] -> @W2^T + b2 [.,18]
__global__ void mlp_head_kernel(const float* __restrict__ hidden,
                                const float* __restrict__ W1, const float* __restrict__ b1,
                                const float* __restrict__ W2, const float* __restrict__ b2,
                                float* __restrict__ out)
{
    const int row = blockIdx.x * blockDim.x + threadIdx.x;   // 0..1535
    if (row >= NL * BB) return;

    float hv[HH];
    #pragma unroll
    for (int k = 0; k < HH; ++k) hv[k] = hidden[row * HH + k];

    float h1[4 * OO];
    #pragma unroll
    for (int m = 0; m < 4 * OO; ++m) {
        float a = b1[m];
        #pragma unroll
        for (int k = 0; k < HH; ++k) a += hv[k] * W1[m * HH + k];
        h1[m] = 0.5f * a * (1.0f + erff(a * 0.70710678118654752f));
    }
    #pragma unroll
    for (int o = 0; o < OO; ++o) {
        float a = b2[o];
        #pragma unroll
        for (int m = 0; m < 4 * OO; ++m) a += h1[m] * W2[o * (4 * OO) + m];
        out[row * OO + o] = a;
    }
}

extern "C" void kernel_launch(void* const* d_in, const int* in_sizes, int n_in,
                              void* d_out, int out_size, void* d_ws, size_t ws_size,
                              hipStream_t stream) {
    const float* x    = (const float*)d_in[0];
    const float* Wih0 = (const float*)d_in[1];
    const float* Whh0 = (const float*)d_in[2];
    const float* bih0 = (const float*)d_in[3];
    const float* bhh0 = (const float*)d_in[4];
    const float* Wih1 = (const float*)d_in[5];
    const float* Whh1 = (const float*)d_in[6];
    const float* bih1 = (const float*)d_in[7];
    const float* bhh1 = (const float*)d_in[8];
    const float* Wih2 = (const float*)d_in[9];
    const float* Whh2 = (const float*)d_in[10];
    const float* bih2 = (const float*)d_in[11];
    const float* bhh2 = (const float*)d_in[12];
    const float* W1   = (const float*)d_in[13];
    const float* b1   = (const float*)d_in[14];
    const float* W2   = (const float*)d_in[15];
    const float* b2   = (const float*)d_in[16];

    float* out    = (float*)d_out;                 // [3,512,18] = 27648 floats
    float* hidden = out + NL * BB * OO;            // [3,512,33] = 50688 floats

    lstm_pipeline_kernel<<<BB, 256, 0, stream>>>(
        x, Wih0, Whh0, bih0, bhh0, Wih1, Whh1, bih1, bhh1,
        Wih2, Whh2, bih2, bhh2, hidden);

    mlp_head_kernel<<<(NL * BB + 255) / 256, 256, 0, stream>>>(
        hidden, W1, b1, W2, b2, out);
}